// Round 1
// baseline (914.887 us; speedup 1.0000x reference)
//
#include <hip/hip_runtime.h>

#define B_ 4
#define C_ 256
#define N_ 4096
#define D_ 64

// ---------------------------------------------------------------------------
// Projection GEMM: Out[b][n][f] = sum_c x[b][c][n] * W[f][c] + bias[f]
// f in [0,64) -> Q[b][n][f], [64,128) -> K[b][n][f-64], [128,384) -> V[b][n][f-128]
// Tiles: 128 n x 128 f, k-chunks of 16, 8x8 register tile per thread.
// ---------------------------------------------------------------------------
__global__ __launch_bounds__(256) void proj_kernel(
    const float* __restrict__ x,
    const float* __restrict__ Wq, const float* __restrict__ bq,
    const float* __restrict__ Wk, const float* __restrict__ bk,
    const float* __restrict__ Wv, const float* __restrict__ bv,
    float* __restrict__ Qg, float* __restrict__ Kg, float* __restrict__ Vg)
{
    __shared__ float As[16][128];   // [cc][n_local]
    __shared__ float Bs[16][128];   // [cc][f_local]
    const int b  = blockIdx.z;
    const int n0 = blockIdx.y * 128;
    const int f0 = blockIdx.x * 128;
    const int t  = threadIdx.x;
    const int iy = t >> 4;          // 0..15 -> rows i0 = iy*8
    const int tx = t & 15;          // 0..15 -> cols f = 2*tx + 32*s + r

    const float* xb = x + (size_t)b * C_ * N_;

    // preload the 8 bias values this thread needs
    float bias[8];
#pragma unroll
    for (int s = 0; s < 4; ++s)
#pragma unroll
        for (int r = 0; r < 2; ++r) {
            int fg = f0 + 2*tx + 32*s + r;
            float bb;
            if (fg < 64)       bb = bq[fg];
            else if (fg < 128) bb = bk[fg - 64];
            else               bb = bv[fg - 128];
            bias[2*s + r] = bb;
        }

    float acc[8][8];
#pragma unroll
    for (int a = 0; a < 8; ++a)
#pragma unroll
        for (int q = 0; q < 8; ++q) acc[a][q] = 0.f;

    for (int c0 = 0; c0 < C_; c0 += 16) {
        __syncthreads();  // previous-iteration LDS reads done before overwrite
        // A tile: x[b][c0+cc][n0 .. n0+128)  (coalesced float4 rows)
#pragma unroll
        for (int k = 0; k < 2; ++k) {
            int e4  = t + 256*k;          // 0..511
            int cc  = e4 >> 5;            // 0..15
            int nn4 = (e4 & 31) << 2;     // 0..124
            float4 v4 = *(const float4*)(xb + (size_t)(c0 + cc)*N_ + n0 + nn4);
            *(float4*)&As[cc][nn4] = v4;
        }
        // B tile: W[f0+fl][c0 .. c0+16), stored transposed into Bs[cc][fl]
#pragma unroll
        for (int k = 0; k < 2; ++k) {
            int e4  = t + 256*k;          // 0..511
            int fl  = e4 >> 2;            // 0..127
            int cc4 = (e4 & 3) << 2;      // 0,4,8,12
            int fg  = f0 + fl;
            const float* wrow = (fg < 64)  ? (Wq + (size_t)fg * C_)
                              : (fg < 128) ? (Wk + (size_t)(fg - 64) * C_)
                                           : (Wv + (size_t)(fg - 128) * C_);
            float4 w4 = *(const float4*)(wrow + c0 + cc4);
            Bs[cc4+0][fl] = w4.x;
            Bs[cc4+1][fl] = w4.y;
            Bs[cc4+2][fl] = w4.z;
            Bs[cc4+3][fl] = w4.w;
        }
        __syncthreads();
#pragma unroll
        for (int cc = 0; cc < 16; ++cc) {
            float4 a0 = *(const float4*)&As[cc][iy*8];
            float4 a1 = *(const float4*)&As[cc][iy*8 + 4];
            float av[8] = {a0.x,a0.y,a0.z,a0.w,a1.x,a1.y,a1.z,a1.w};
            float bvv[8];
#pragma unroll
            for (int s = 0; s < 4; ++s) {
                float2 b2 = *(const float2*)&Bs[cc][2*tx + 32*s];
                bvv[2*s] = b2.x; bvv[2*s+1] = b2.y;
            }
#pragma unroll
            for (int a = 0; a < 8; ++a)
#pragma unroll
                for (int q = 0; q < 8; ++q)
                    acc[a][q] += av[a] * bvv[q];
        }
    }

    // epilogue: route to Q/K/V with bias
#pragma unroll
    for (int a = 0; a < 8; ++a) {
        int n = n0 + iy*8 + a;
#pragma unroll
        for (int s = 0; s < 4; ++s) {
            int fg = f0 + 2*tx + 32*s;
            float2 val;
            val.x = acc[a][2*s]   + bias[2*s];
            val.y = acc[a][2*s+1] + bias[2*s+1];
            float* dst;
            if (fg < 64)       dst = Qg + ((size_t)b*N_ + n)*D_ + fg;
            else if (fg < 128) dst = Kg + ((size_t)b*N_ + n)*D_ + (fg - 64);
            else               dst = Vg + ((size_t)b*N_ + n)*C_ + (fg - 128);
            *(float2*)dst = val;
        }
    }
}

// ---------------------------------------------------------------------------
// Flash attention (fp32). One block = one (batch, 64-query-row tile).
// Streams K/V in 32-key chunks via LDS; online softmax; fused epilogue
// y = gamma * O/l + x written coalesced via LDS staging.
// LDS budget (static, 57856 B):
//   Qst [64][64]   d-major Q tile, 16 KB       (b128 reads, <=2-way banks)
//   Vs  [32][256]  V tile, 32 KB               (b128 reads, 2-way banks)
//   KP  union { Kst[64][33] , Pt[32][68] } 8704 B
//   Os  [128][68] epilogue overlay on Vs+KP
// ---------------------------------------------------------------------------
#define TK 32

__global__ __launch_bounds__(256) void flash_kernel(
    const float* __restrict__ Qg, const float* __restrict__ Kg,
    const float* __restrict__ Vg, const float* __restrict__ x,
    const float* __restrict__ gamma, float* __restrict__ out)
{
    __shared__ __align__(16) char smem[57856];
    float* Qst = (float*)smem;                 // Qst[d*64 + i]
    float* Vs  = (float*)(smem + 16384);       // Vs[j*256 + c]
    float* KP  = (float*)(smem + 49152);       // Kst[d*33+j]  /  Pt[j*68+i]
    float* Os  = (float*)(smem + 16384);       // Os[c*68 + i] (overlay)

    const int b  = blockIdx.y;
    const int n0 = blockIdx.x * 64;
    const int t  = threadIdx.x;
    const int iy = t >> 4;       // 0..15
    const int tx = t & 15;       // 0..15
    const int i0 = iy * 4;       // this thread's 4 query rows

    const float* Qb = Qg + ((size_t)b*N_ + n0)*D_;
    const float* Kb = Kg + (size_t)b*N_*D_;
    const float* Vb = Vg + (size_t)b*N_*C_;

    // Q tile -> LDS, transposed to d-major (done once)
#pragma unroll
    for (int k = 0; k < 4; ++k) {
        int e4 = t + 256*k;           // 0..1023
        int i  = e4 >> 4;             // 0..63
        int d4 = (e4 & 15) << 2;      // 0..60
        float4 q4 = *(const float4*)(Qb + (size_t)i*D_ + d4);
        Qst[(d4+0)*64 + i] = q4.x;
        Qst[(d4+1)*64 + i] = q4.y;
        Qst[(d4+2)*64 + i] = q4.z;
        Qst[(d4+3)*64 + i] = q4.w;
    }

    float m_r[4], l_r[4];
    float acc_o[4][4][4];   // [row r][c-block s][c-offset q]; c = 4*tx + 64*s + q
#pragma unroll
    for (int r = 0; r < 4; ++r) {
        m_r[r] = -1e30f; l_r[r] = 0.f;
#pragma unroll
        for (int s = 0; s < 4; ++s)
#pragma unroll
            for (int q = 0; q < 4; ++q) acc_o[r][s][q] = 0.f;
    }

    for (int j0 = 0; j0 < N_; j0 += TK) {
        __syncthreads();   // prior PV reads (and Q staging) done
        // K chunk -> Kst transposed: Kst[d][j]
#pragma unroll
        for (int k = 0; k < 2; ++k) {
            int e4 = t + 256*k;       // 0..511
            int j  = e4 >> 4;         // 0..31
            int d4 = (e4 & 15) << 2;  // 0..60
            float4 k4 = *(const float4*)(Kb + (size_t)(j0 + j)*D_ + d4);
            KP[(d4+0)*33 + j] = k4.x;
            KP[(d4+1)*33 + j] = k4.y;
            KP[(d4+2)*33 + j] = k4.z;
            KP[(d4+3)*33 + j] = k4.w;
        }
        // V chunk -> Vs: Vs[j][c]
#pragma unroll
        for (int k = 0; k < 8; ++k) {
            int e4 = t + 256*k;       // 0..2047
            int j  = e4 >> 6;         // 0..31
            int c4 = (e4 & 63) << 2;  // 0..252
            float4 v4 = *(const float4*)(Vb + (size_t)(j0 + j)*C_ + c4);
            *(float4*)&Vs[j*256 + c4] = v4;
        }
        __syncthreads();

        // S[i][j] = sum_d Q[i][d] K[j][d]; this thread: rows i0..i0+3, j in {tx, tx+16}
        float acc_s[4][2];
#pragma unroll
        for (int r = 0; r < 4; ++r) { acc_s[r][0] = 0.f; acc_s[r][1] = 0.f; }
#pragma unroll 4
        for (int d = 0; d < 64; ++d) {
            float4 q4 = *(const float4*)&Qst[d*64 + i0];
            float k0 = KP[d*33 + tx];
            float k1 = KP[d*33 + tx + 16];
            acc_s[0][0] += q4.x*k0; acc_s[0][1] += q4.x*k1;
            acc_s[1][0] += q4.y*k0; acc_s[1][1] += q4.y*k1;
            acc_s[2][0] += q4.z*k0; acc_s[2][1] += q4.z*k1;
            acc_s[3][0] += q4.w*k0; acc_s[3][1] += q4.w*k1;
        }
        __syncthreads();   // all Kst reads done -> KP region reusable as Pt

        // online softmax across the 16 tx-lanes holding each row
        float alpha[4];
#pragma unroll
        for (int r = 0; r < 4; ++r) {
            float mx = fmaxf(acc_s[r][0], acc_s[r][1]);
#pragma unroll
            for (int off = 1; off <= 8; off <<= 1)
                mx = fmaxf(mx, __shfl_xor(mx, off));
            float mnew = fmaxf(m_r[r], mx);
            alpha[r] = __expf(m_r[r] - mnew);
            float p0 = __expf(acc_s[r][0] - mnew);
            float p1 = __expf(acc_s[r][1] - mnew);
            float sm = p0 + p1;
#pragma unroll
            for (int off = 1; off <= 8; off <<= 1)
                sm += __shfl_xor(sm, off);
            l_r[r] = l_r[r]*alpha[r] + sm;
            m_r[r] = mnew;
            KP[tx*68 + i0 + r]        = p0;   // Pt[j][i]
            KP[(tx+16)*68 + i0 + r]   = p1;
        }
        __syncthreads();

        // O = alpha*O + P V
#pragma unroll
        for (int r = 0; r < 4; ++r)
#pragma unroll
            for (int s = 0; s < 4; ++s)
#pragma unroll
                for (int q = 0; q < 4; ++q) acc_o[r][s][q] *= alpha[r];

#pragma unroll 4
        for (int j = 0; j < TK; ++j) {
            float4 p4 = *(const float4*)&KP[j*68 + i0];
            float4 vv[4];
            vv[0] = *(const float4*)&Vs[j*256 + 4*tx];
            vv[1] = *(const float4*)&Vs[j*256 + 4*tx + 64];
            vv[2] = *(const float4*)&Vs[j*256 + 4*tx + 128];
            vv[3] = *(const float4*)&Vs[j*256 + 4*tx + 192];
            float pr[4] = {p4.x, p4.y, p4.z, p4.w};
#pragma unroll
            for (int r = 0; r < 4; ++r)
#pragma unroll
                for (int s = 0; s < 4; ++s) {
                    acc_o[r][s][0] += pr[r]*vv[s].x;
                    acc_o[r][s][1] += pr[r]*vv[s].y;
                    acc_o[r][s][2] += pr[r]*vv[s].z;
                    acc_o[r][s][3] += pr[r]*vv[s].w;
                }
        }
    }

    // epilogue: y[b][c][n] = gamma * O[i][c]/l[i] + x[b][c][n], coalesced via LDS
    float g = gamma[0];
    float inv_l[4];
#pragma unroll
    for (int r = 0; r < 4; ++r) inv_l[r] = 1.f / l_r[r];

    const float* xb = x   + (size_t)b*C_*N_;
    float*       ob = out + (size_t)b*C_*N_;

#pragma unroll
    for (int h = 0; h < 2; ++h) {      // two 128-channel halves
        __syncthreads();               // Vs/KP reads done before overlay write
#pragma unroll
        for (int sh = 0; sh < 2; ++sh) {
            int s = 2*h + sh;
#pragma unroll
            for (int q = 0; q < 4; ++q) {
                int cp = 4*tx + 64*sh + q;    // channel within half
#pragma unroll
                for (int r = 0; r < 4; ++r)
                    Os[cp*68 + i0 + r] = g * acc_o[r][s][q] * inv_l[r];
            }
        }
        __syncthreads();
#pragma unroll
        for (int k = 0; k < 8; ++k) {
            int e4  = t + 256*k;       // 0..2047
            int cp  = e4 >> 4;         // 0..127
            int nn4 = (e4 & 15) << 2;  // 0..60
            int c   = 128*h + cp;
            float4 o4 = *(const float4*)&Os[cp*68 + nn4];
            float4 x4 = *(const float4*)(xb + (size_t)c*N_ + n0 + nn4);
            float4 y4;
            y4.x = o4.x + x4.x; y4.y = o4.y + x4.y;
            y4.z = o4.z + x4.z; y4.w = o4.w + x4.w;
            *(float4*)(ob + (size_t)c*N_ + n0 + nn4) = y4;
        }
    }
}

// ---------------------------------------------------------------------------
extern "C" void kernel_launch(void* const* d_in, const int* in_sizes, int n_in,
                              void* d_out, int out_size, void* d_ws, size_t ws_size,
                              hipStream_t stream) {
    const float* x     = (const float*)d_in[0];
    const float* Wq    = (const float*)d_in[1];
    const float* bq    = (const float*)d_in[2];
    const float* Wk    = (const float*)d_in[3];
    const float* bk    = (const float*)d_in[4];
    const float* Wv    = (const float*)d_in[5];
    const float* bv    = (const float*)d_in[6];
    const float* gamma = (const float*)d_in[7];
    float* out = (float*)d_out;

    float* Qg = (float*)d_ws;                       // [B][N][64]   4 MB
    float* Kg = Qg + (size_t)B_*N_*D_;              // [B][N][64]   4 MB
    float* Vg = Kg + (size_t)B_*N_*D_;              // [B][N][256] 16 MB

    proj_kernel<<<dim3(3, 32, 4), 256, 0, stream>>>(x, Wq, bq, Wk, bk, Wv, bv,
                                                    Qg, Kg, Vg);
    flash_kernel<<<dim3(64, 4), 256, 0, stream>>>(Qg, Kg, Vg, x, gamma, out);
}

// Round 2
// 314.089 us; speedup vs baseline: 2.9128x; 2.9128x over previous
//
#include <hip/hip_runtime.h>

#define B_ 4
#define C_ 256
#define N_ 4096
#define D_ 64

typedef __bf16 bf16x8 __attribute__((ext_vector_type(8)));
typedef float floatx4 __attribute__((ext_vector_type(4)));
typedef unsigned short ushort8v __attribute__((ext_vector_type(8)));
typedef unsigned short ushort2v __attribute__((ext_vector_type(2)));

static __device__ __forceinline__ unsigned short f2bf(float f) {
    unsigned int u = __builtin_bit_cast(unsigned int, f);
    u += 0x7fffu + ((u >> 16) & 1u);   // RNE
    return (unsigned short)(u >> 16);
}

// ---------------------------------------------------------------------------
// Projection GEMM: f in [0,64) -> Q[b][n][d] bf16, [64,128) -> K[b][n][d] bf16,
// [128,384) -> V[b][c][n] bf16 (c-major, transposed store).
// fp32 compute, 128x128 tiles, 8x8 register tile per thread.
// ---------------------------------------------------------------------------
__global__ __launch_bounds__(256) void proj_kernel(
    const float* __restrict__ x,
    const float* __restrict__ Wq, const float* __restrict__ bq,
    const float* __restrict__ Wk, const float* __restrict__ bk,
    const float* __restrict__ Wv, const float* __restrict__ bv,
    unsigned short* __restrict__ Qg, unsigned short* __restrict__ Kg,
    unsigned short* __restrict__ Vg)
{
    __shared__ float As[16][128];   // [cc][n_local]
    __shared__ float Bs[16][128];   // [cc][f_local]
    const int b  = blockIdx.z;
    const int n0 = blockIdx.y * 128;
    const int f0 = blockIdx.x * 128;
    const int t  = threadIdx.x;
    const int iy = t >> 4;          // 0..15 -> rows i0 = iy*8
    const int tx = t & 15;          // 0..15 -> cols f = 2*tx + 32*s + r

    const float* xb = x + (size_t)b * C_ * N_;

    float bias[8];
#pragma unroll
    for (int s = 0; s < 4; ++s)
#pragma unroll
        for (int r = 0; r < 2; ++r) {
            int fg = f0 + 2*tx + 32*s + r;
            float bb;
            if (fg < 64)       bb = bq[fg];
            else if (fg < 128) bb = bk[fg - 64];
            else               bb = bv[fg - 128];
            bias[2*s + r] = bb;
        }

    float acc[8][8];
#pragma unroll
    for (int a = 0; a < 8; ++a)
#pragma unroll
        for (int q = 0; q < 8; ++q) acc[a][q] = 0.f;

    for (int c0 = 0; c0 < C_; c0 += 16) {
        __syncthreads();
#pragma unroll
        for (int k = 0; k < 2; ++k) {
            int e4  = t + 256*k;
            int cc  = e4 >> 5;
            int nn4 = (e4 & 31) << 2;
            float4 v4 = *(const float4*)(xb + (size_t)(c0 + cc)*N_ + n0 + nn4);
            *(float4*)&As[cc][nn4] = v4;
        }
#pragma unroll
        for (int k = 0; k < 2; ++k) {
            int e4  = t + 256*k;
            int fl  = e4 >> 2;
            int cc4 = (e4 & 3) << 2;
            int fg  = f0 + fl;
            const float* wrow = (fg < 64)  ? (Wq + (size_t)fg * C_)
                              : (fg < 128) ? (Wk + (size_t)(fg - 64) * C_)
                                           : (Wv + (size_t)(fg - 128) * C_);
            float4 w4 = *(const float4*)(wrow + c0 + cc4);
            Bs[cc4+0][fl] = w4.x;
            Bs[cc4+1][fl] = w4.y;
            Bs[cc4+2][fl] = w4.z;
            Bs[cc4+3][fl] = w4.w;
        }
        __syncthreads();
#pragma unroll
        for (int cc = 0; cc < 16; ++cc) {
            float4 a0 = *(const float4*)&As[cc][iy*8];
            float4 a1 = *(const float4*)&As[cc][iy*8 + 4];
            float av[8] = {a0.x,a0.y,a0.z,a0.w,a1.x,a1.y,a1.z,a1.w};
            float bvv[8];
#pragma unroll
            for (int s = 0; s < 4; ++s) {
                float2 b2 = *(const float2*)&Bs[cc][2*tx + 32*s];
                bvv[2*s] = b2.x; bvv[2*s+1] = b2.y;
            }
#pragma unroll
            for (int a = 0; a < 8; ++a)
#pragma unroll
                for (int q = 0; q < 8; ++q)
                    acc[a][q] += av[a] * bvv[q];
        }
    }

    if (f0 < 128) {
        // Q/K tiles: store [n][64] bf16, ushort2 per (s)
#pragma unroll
        for (int a = 0; a < 8; ++a) {
            int n = n0 + iy*8 + a;
#pragma unroll
            for (int s = 0; s < 4; ++s) {
                int fg = 2*tx + 32*s;   // f0 == 0
                ushort2v u2;
                u2.x = f2bf(acc[a][2*s]   + bias[2*s]);
                u2.y = f2bf(acc[a][2*s+1] + bias[2*s+1]);
                unsigned short* dst = (fg < 64)
                    ? (Qg + ((size_t)b*N_ + n)*D_ + fg)
                    : (Kg + ((size_t)b*N_ + n)*D_ + (fg - 64));
                *(ushort2v*)dst = u2;
            }
        }
    } else {
        // V tiles: transposed store [c][n] bf16, 8 n's (16B) per (s,r)
#pragma unroll
        for (int s = 0; s < 4; ++s)
#pragma unroll
            for (int r = 0; r < 2; ++r) {
                int c = (f0 - 128) + 2*tx + 32*s + r;
                ushort8v u8;
#pragma unroll
                for (int a = 0; a < 8; ++a)
                    u8[a] = f2bf(acc[a][2*s + r] + bias[2*s + r]);
                *(ushort8v*)(Vg + ((size_t)b*C_ + c)*N_ + n0 + iy*8) = u8;
            }
    }
}

// ---------------------------------------------------------------------------
// MFMA flash attention. Block = (batch, 64-query tile), 4 waves.
// S-phase: row-split (16 q-rows/wave), K frags direct from global (prefetched
// one chunk ahead). Softmax in C-layout regs, shfl-xor reductions over lanes
// 0..15 (rows live in (lane>>4)*4+reg). P -> LDS in A-frag-native
// lane-contiguous layout (double buffered), alpha broadcast via LDS.
// PV-phase: channel-split (64 ch/wave), V frags direct from global (c-major),
// 32 MFMA/chunk/wave. One barrier per chunk.
// ---------------------------------------------------------------------------
__global__ __launch_bounds__(256, 1) void flash_kernel(
    const unsigned short* __restrict__ Qg, const unsigned short* __restrict__ Kg,
    const unsigned short* __restrict__ Vg, const float* __restrict__ x,
    const float* __restrict__ gamma, float* __restrict__ out)
{
    __shared__ __align__(16) unsigned short PA[2][8 * 64 * 8]; // [buf][(rt*2+ks)*64 + lane][8]
    __shared__ float AL[2][64];
    __shared__ float LL[64];

    const int b    = blockIdx.y;
    const int n0   = blockIdx.x * 64;
    const int t    = threadIdx.x;
    const int w    = t >> 6;        // wave 0..3
    const int lane = t & 63;
    const int g    = lane >> 4;     // quad 0..3
    const int m    = lane & 15;

    const unsigned short* Qb = Qg + ((size_t)b*N_ + n0)*D_;
    const unsigned short* Kb = Kg + (size_t)b*N_*D_;
    const unsigned short* Vb = Vg + (size_t)b*C_*N_;

    // Q A-frags for this wave's rows (16w + m), k-windows ks=0,1 (persist)
    bf16x8 qf[2];
#pragma unroll
    for (int ks = 0; ks < 2; ++ks)
        qf[ks] = *(const bf16x8*)(Qb + (size_t)(16*w + m)*D_ + 32*ks + 8*g);

    floatx4 accO[4][4];             // [rt][ct]: rows rt*16+4g+reg, col 64w+16ct+m
#pragma unroll
    for (int rt = 0; rt < 4; ++rt)
#pragma unroll
        for (int ct = 0; ct < 4; ++ct)
            accO[rt][ct] = (floatx4){0.f, 0.f, 0.f, 0.f};

    float mrow[4], lrow[4];
#pragma unroll
    for (int r = 0; r < 4; ++r) { mrow[r] = -1e30f; lrow[r] = 0.f; }

    // K B-frags for chunk 0
    bf16x8 kf[2][4];
#pragma unroll
    for (int ks = 0; ks < 2; ++ks)
#pragma unroll
        for (int jt = 0; jt < 4; ++jt)
            kf[ks][jt] = *(const bf16x8*)(Kb + (size_t)(16*jt + m)*D_ + 32*ks + 8*g);

    for (int t64 = 0; t64 < N_/64; ++t64) {
        const int j0  = t64 * 64;
        const int buf = t64 & 1;

        // ---- issue V frag loads for this chunk (land during S+softmax) ----
        bf16x8 vf[2][4];
#pragma unroll
        for (int ks = 0; ks < 2; ++ks)
#pragma unroll
            for (int ct = 0; ct < 4; ++ct)
                vf[ks][ct] = *(const bf16x8*)(Vb + (size_t)(64*w + 16*ct + m)*N_
                                              + j0 + 32*ks + 8*g);

        // ---- S = Q K^T for this wave's 16 rows x 64 keys ----
        floatx4 accS[4];
#pragma unroll
        for (int jt = 0; jt < 4; ++jt) accS[jt] = (floatx4){0.f, 0.f, 0.f, 0.f};
#pragma unroll
        for (int ks = 0; ks < 2; ++ks)
#pragma unroll
            for (int jt = 0; jt < 4; ++jt)
                accS[jt] = __builtin_amdgcn_mfma_f32_16x16x32_bf16(
                               qf[ks], kf[ks][jt], accS[jt], 0, 0, 0);

        // ---- prefetch next chunk's K frags (wrap on last iter; unused) ----
        {
            int j1 = (j0 + 64) & (N_ - 1);
#pragma unroll
            for (int ks = 0; ks < 2; ++ks)
#pragma unroll
                for (int jt = 0; jt < 4; ++jt)
                    kf[ks][jt] = *(const bf16x8*)(Kb + (size_t)(j1 + 16*jt + m)*D_
                                                  + 32*ks + 8*g);
        }

        // ---- online softmax (rows = rt w, row-in-wave = 4g+reg) ----
        float pv[4][4];    // [jt][r]
        float alpha[4];
#pragma unroll
        for (int r = 0; r < 4; ++r) {
            float mx = fmaxf(fmaxf(accS[0][r], accS[1][r]),
                             fmaxf(accS[2][r], accS[3][r]));
            mx = fmaxf(mx, __shfl_xor(mx, 1));
            mx = fmaxf(mx, __shfl_xor(mx, 2));
            mx = fmaxf(mx, __shfl_xor(mx, 4));
            mx = fmaxf(mx, __shfl_xor(mx, 8));
            float mnew = fmaxf(mrow[r], mx);
            alpha[r] = __expf(mrow[r] - mnew);
            mrow[r] = mnew;
            float rs = 0.f;
#pragma unroll
            for (int jt = 0; jt < 4; ++jt) {
                float p = __expf(accS[jt][r] - mnew);
                pv[jt][r] = p;
                rs += p;
            }
            rs += __shfl_xor(rs, 1);
            rs += __shfl_xor(rs, 2);
            rs += __shfl_xor(rs, 4);
            rs += __shfl_xor(rs, 8);
            lrow[r] = lrow[r] * alpha[r] + rs;
        }

        // alpha broadcast: lanes m==0 hold rows 16w+4g+0..3
        if (m == 0) {
            floatx4 a4 = {alpha[0], alpha[1], alpha[2], alpha[3]};
            *(floatx4*)&AL[buf][16*w + 4*g] = a4;
        }

        // P -> LDS (bf16), pair-packed b32 writes into A-frag-native layout
#pragma unroll
        for (int jt = 0; jt < 4; ++jt)
#pragma unroll
            for (int r = 0; r < 4; ++r) {
                float other = __shfl_xor(pv[jt][r], 1);
                if ((lane & 1) == 0) {
                    ushort2v u2;
                    u2.x = f2bf(pv[jt][r]);
                    u2.y = f2bf(other);
                    int frag = (w*2 + (jt >> 1))*64
                             + ((2*jt + (m >> 3)) & 3)*16 + 4*g + r;
                    *(ushort2v*)&PA[buf][frag*8 + (m & 7)] = u2;
                }
            }

        __syncthreads();

        // ---- PV phase: O = alpha*O + P V  (this wave: channels 64w..64w+63)
#pragma unroll
        for (int rt = 0; rt < 4; ++rt) {
            floatx4 a4 = *(const floatx4*)&AL[buf][16*rt + 4*g];
#pragma unroll
            for (int ct = 0; ct < 4; ++ct)
                accO[rt][ct] *= a4;
        }
#pragma unroll
        for (int ks = 0; ks < 2; ++ks) {
            bf16x8 pf[4];
#pragma unroll
            for (int rt = 0; rt < 4; ++rt)
                pf[rt] = *(const bf16x8*)&PA[buf][((rt*2 + ks)*64 + lane)*8];
#pragma unroll
            for (int ct = 0; ct < 4; ++ct)
#pragma unroll
                for (int rt = 0; rt < 4; ++rt)
                    accO[rt][ct] = __builtin_amdgcn_mfma_f32_16x16x32_bf16(
                                       pf[rt], vf[ks][ct], accO[rt][ct], 0, 0, 0);
        }
    }

    // ---- epilogue: broadcast l, then y = gamma*O/l + x (float4 stores) ----
    if (m == 0) {
        floatx4 l4 = {lrow[0], lrow[1], lrow[2], lrow[3]};
        *(floatx4*)&LL[16*w + 4*g] = l4;
    }
    __syncthreads();

    const float gm = gamma[0];
    const float* xb = x   + (size_t)b*C_*N_;
    float*       ob = out + (size_t)b*C_*N_;
#pragma unroll
    for (int rt = 0; rt < 4; ++rt) {
        floatx4 l4 = *(const floatx4*)&LL[16*rt + 4*g];
        floatx4 sc = {gm / l4[0], gm / l4[1], gm / l4[2], gm / l4[3]};
#pragma unroll
        for (int ct = 0; ct < 4; ++ct) {
            int c = 64*w + 16*ct + m;
            size_t base = (size_t)c*N_ + n0 + 16*rt + 4*g;
            floatx4 x4 = *(const floatx4*)(xb + base);
            floatx4 y  = accO[rt][ct] * sc + x4;
            *(floatx4*)(ob + base) = y;
        }
    }
}

// ---------------------------------------------------------------------------
extern "C" void kernel_launch(void* const* d_in, const int* in_sizes, int n_in,
                              void* d_out, int out_size, void* d_ws, size_t ws_size,
                              hipStream_t stream) {
    const float* x     = (const float*)d_in[0];
    const float* Wq    = (const float*)d_in[1];
    const float* bq    = (const float*)d_in[2];
    const float* Wk    = (const float*)d_in[3];
    const float* bk    = (const float*)d_in[4];
    const float* Wv    = (const float*)d_in[5];
    const float* bv    = (const float*)d_in[6];
    const float* gamma = (const float*)d_in[7];
    float* out = (float*)d_out;

    unsigned short* Qg = (unsigned short*)d_ws;          // [B][N][64]  2 MB
    unsigned short* Kg = Qg + (size_t)B_*N_*D_;          // [B][N][64]  2 MB
    unsigned short* Vg = Kg + (size_t)B_*N_*D_;          // [B][C][N]   8 MB

    proj_kernel<<<dim3(3, 32, 4), 256, 0, stream>>>(x, Wq, bq, Wk, bk, Wv, bv,
                                                    Qg, Kg, Vg);
    flash_kernel<<<dim3(64, 4), 256, 0, stream>>>(Qg, Kg, Vg, x, gamma, out);
}

// Round 3
// 259.924 us; speedup vs baseline: 3.5198x; 1.2084x over previous
//
#include <hip/hip_runtime.h>

#define B_ 4
#define C_ 256
#define N_ 4096
#define D_ 64

typedef __bf16 bf16x8 __attribute__((ext_vector_type(8)));
typedef float floatx4 __attribute__((ext_vector_type(4)));
typedef unsigned short ushort8v __attribute__((ext_vector_type(8)));
typedef unsigned short ushort4v __attribute__((ext_vector_type(4)));
typedef unsigned short ushort2v __attribute__((ext_vector_type(2)));

static __device__ __forceinline__ unsigned short f2bf(float f) {
    unsigned int u = __builtin_bit_cast(unsigned int, f);
    u += 0x7fffu + ((u >> 16) & 1u);   // RNE
    return (unsigned short)(u >> 16);
}
static __device__ __forceinline__ float bf2f(unsigned short h) {
    unsigned int u = ((unsigned int)h) << 16;
    return __builtin_bit_cast(float, u);
}

// ---------------------------------------------------------------------------
// Projection GEMM (unchanged this round): fp32 compute,
// f in [0,64) -> Q[b][n][d] bf16, [64,128) -> K[b][n][d] bf16,
// [128,384) -> V[b][c][n] bf16 (c-major, transposed store).
// ---------------------------------------------------------------------------
__global__ __launch_bounds__(256) void proj_kernel(
    const float* __restrict__ x,
    const float* __restrict__ Wq, const float* __restrict__ bq,
    const float* __restrict__ Wk, const float* __restrict__ bk,
    const float* __restrict__ Wv, const float* __restrict__ bv,
    unsigned short* __restrict__ Qg, unsigned short* __restrict__ Kg,
    unsigned short* __restrict__ Vg)
{
    __shared__ float As[16][128];
    __shared__ float Bs[16][128];
    const int b  = blockIdx.z;
    const int n0 = blockIdx.y * 128;
    const int f0 = blockIdx.x * 128;
    const int t  = threadIdx.x;
    const int iy = t >> 4;
    const int tx = t & 15;

    const float* xb = x + (size_t)b * C_ * N_;

    float bias[8];
#pragma unroll
    for (int s = 0; s < 4; ++s)
#pragma unroll
        for (int r = 0; r < 2; ++r) {
            int fg = f0 + 2*tx + 32*s + r;
            float bb;
            if (fg < 64)       bb = bq[fg];
            else if (fg < 128) bb = bk[fg - 64];
            else               bb = bv[fg - 128];
            bias[2*s + r] = bb;
        }

    float acc[8][8];
#pragma unroll
    for (int a = 0; a < 8; ++a)
#pragma unroll
        for (int q = 0; q < 8; ++q) acc[a][q] = 0.f;

    for (int c0 = 0; c0 < C_; c0 += 16) {
        __syncthreads();
#pragma unroll
        for (int k = 0; k < 2; ++k) {
            int e4  = t + 256*k;
            int cc  = e4 >> 5;
            int nn4 = (e4 & 31) << 2;
            float4 v4 = *(const float4*)(xb + (size_t)(c0 + cc)*N_ + n0 + nn4);
            *(float4*)&As[cc][nn4] = v4;
        }
#pragma unroll
        for (int k = 0; k < 2; ++k) {
            int e4  = t + 256*k;
            int fl  = e4 >> 2;
            int cc4 = (e4 & 3) << 2;
            int fg  = f0 + fl;
            const float* wrow = (fg < 64)  ? (Wq + (size_t)fg * C_)
                              : (fg < 128) ? (Wk + (size_t)(fg - 64) * C_)
                                           : (Wv + (size_t)(fg - 128) * C_);
            float4 w4 = *(const float4*)(wrow + c0 + cc4);
            Bs[cc4+0][fl] = w4.x;
            Bs[cc4+1][fl] = w4.y;
            Bs[cc4+2][fl] = w4.z;
            Bs[cc4+3][fl] = w4.w;
        }
        __syncthreads();
#pragma unroll
        for (int cc = 0; cc < 16; ++cc) {
            float4 a0 = *(const float4*)&As[cc][iy*8];
            float4 a1 = *(const float4*)&As[cc][iy*8 + 4];
            float av[8] = {a0.x,a0.y,a0.z,a0.w,a1.x,a1.y,a1.z,a1.w};
            float bvv[8];
#pragma unroll
            for (int s = 0; s < 4; ++s) {
                float2 b2 = *(const float2*)&Bs[cc][2*tx + 32*s];
                bvv[2*s] = b2.x; bvv[2*s+1] = b2.y;
            }
#pragma unroll
            for (int a = 0; a < 8; ++a)
#pragma unroll
                for (int q = 0; q < 8; ++q)
                    acc[a][q] += av[a] * bvv[q];
        }
    }

    if (f0 < 128) {
#pragma unroll
        for (int a = 0; a < 8; ++a) {
            int n = n0 + iy*8 + a;
#pragma unroll
            for (int s = 0; s < 4; ++s) {
                int fg = 2*tx + 32*s;
                ushort2v u2;
                u2.x = f2bf(acc[a][2*s]   + bias[2*s]);
                u2.y = f2bf(acc[a][2*s+1] + bias[2*s+1]);
                unsigned short* dst = (fg < 64)
                    ? (Qg + ((size_t)b*N_ + n)*D_ + fg)
                    : (Kg + ((size_t)b*N_ + n)*D_ + (fg - 64));
                *(ushort2v*)dst = u2;
            }
        }
    } else {
#pragma unroll
        for (int s = 0; s < 4; ++s)
#pragma unroll
            for (int r = 0; r < 2; ++r) {
                int c = (f0 - 128) + 2*tx + 32*s + r;
                ushort8v u8;
#pragma unroll
                for (int a = 0; a < 8; ++a)
                    u8[a] = f2bf(acc[a][2*s + r] + bias[2*s + r]);
                *(ushort8v*)(Vg + ((size_t)b*C_ + c)*N_ + n0 + iy*8) = u8;
            }
    }
}

// ---------------------------------------------------------------------------
// MFMA flash attention, split-K 2-way. Block = (64-query tile, key-half,
// batch); 512 blocks -> 2 blocks/CU. Each block runs 32 key-chunks and emits
// UNNORMALIZED partial O (bf16) plus per-row (m, l) for the combine pass.
// ---------------------------------------------------------------------------
__global__ __launch_bounds__(256, 2) void flash_kernel(
    const unsigned short* __restrict__ Qg, const unsigned short* __restrict__ Kg,
    const unsigned short* __restrict__ Vg,
    unsigned short* __restrict__ Opart, float* __restrict__ ML)
{
    __shared__ __align__(16) unsigned short PA[2][8 * 64 * 8];
    __shared__ float AL[2][64];

    const int tile = blockIdx.x;
    const int half = blockIdx.y;
    const int b    = blockIdx.z;
    const int n0   = tile * 64;
    const int t    = threadIdx.x;
    const int w    = t >> 6;
    const int lane = t & 63;
    const int g    = lane >> 4;
    const int m    = lane & 15;

    const unsigned short* Qb = Qg + ((size_t)b*N_ + n0)*D_;
    const unsigned short* Kb = Kg + (size_t)b*N_*D_;
    const unsigned short* Vb = Vg + (size_t)b*C_*N_;
    const int jbase = half * (N_/2);

    bf16x8 qf[2];
#pragma unroll
    for (int ks = 0; ks < 2; ++ks)
        qf[ks] = *(const bf16x8*)(Qb + (size_t)(16*w + m)*D_ + 32*ks + 8*g);

    floatx4 accO[4][4];
#pragma unroll
    for (int rt = 0; rt < 4; ++rt)
#pragma unroll
        for (int ct = 0; ct < 4; ++ct)
            accO[rt][ct] = (floatx4){0.f, 0.f, 0.f, 0.f};

    float mrow[4], lrow[4];
#pragma unroll
    for (int r = 0; r < 4; ++r) { mrow[r] = -1e30f; lrow[r] = 0.f; }

    bf16x8 kf[2][4];
#pragma unroll
    for (int ks = 0; ks < 2; ++ks)
#pragma unroll
        for (int jt = 0; jt < 4; ++jt)
            kf[ks][jt] = *(const bf16x8*)(Kb + (size_t)(jbase + 16*jt + m)*D_
                                          + 32*ks + 8*g);

    for (int t64 = 0; t64 < N_/128; ++t64) {
        const int j0  = jbase + t64 * 64;
        const int buf = t64 & 1;

        bf16x8 vf[2][4];
#pragma unroll
        for (int ks = 0; ks < 2; ++ks)
#pragma unroll
            for (int ct = 0; ct < 4; ++ct)
                vf[ks][ct] = *(const bf16x8*)(Vb + (size_t)(64*w + 16*ct + m)*N_
                                              + j0 + 32*ks + 8*g);

        floatx4 accS[4];
#pragma unroll
        for (int jt = 0; jt < 4; ++jt) accS[jt] = (floatx4){0.f, 0.f, 0.f, 0.f};
#pragma unroll
        for (int ks = 0; ks < 2; ++ks)
#pragma unroll
            for (int jt = 0; jt < 4; ++jt)
                accS[jt] = __builtin_amdgcn_mfma_f32_16x16x32_bf16(
                               qf[ks], kf[ks][jt], accS[jt], 0, 0, 0);

        {
            int j1 = (j0 + 64) & (N_ - 1);
#pragma unroll
            for (int ks = 0; ks < 2; ++ks)
#pragma unroll
                for (int jt = 0; jt < 4; ++jt)
                    kf[ks][jt] = *(const bf16x8*)(Kb + (size_t)(j1 + 16*jt + m)*D_
                                                  + 32*ks + 8*g);
        }

        float pv[4][4];
        float alpha[4];
#pragma unroll
        for (int r = 0; r < 4; ++r) {
            float mx = fmaxf(fmaxf(accS[0][r], accS[1][r]),
                             fmaxf(accS[2][r], accS[3][r]));
            mx = fmaxf(mx, __shfl_xor(mx, 1));
            mx = fmaxf(mx, __shfl_xor(mx, 2));
            mx = fmaxf(mx, __shfl_xor(mx, 4));
            mx = fmaxf(mx, __shfl_xor(mx, 8));
            float mnew = fmaxf(mrow[r], mx);
            alpha[r] = __expf(mrow[r] - mnew);
            mrow[r] = mnew;
            float rs = 0.f;
#pragma unroll
            for (int jt = 0; jt < 4; ++jt) {
                float p = __expf(accS[jt][r] - mnew);
                pv[jt][r] = p;
                rs += p;
            }
            rs += __shfl_xor(rs, 1);
            rs += __shfl_xor(rs, 2);
            rs += __shfl_xor(rs, 4);
            rs += __shfl_xor(rs, 8);
            lrow[r] = lrow[r] * alpha[r] + rs;
        }

        if (m == 0) {
            floatx4 a4 = {alpha[0], alpha[1], alpha[2], alpha[3]};
            *(floatx4*)&AL[buf][16*w + 4*g] = a4;
        }

#pragma unroll
        for (int jt = 0; jt < 4; ++jt)
#pragma unroll
            for (int r = 0; r < 4; ++r) {
                float other = __shfl_xor(pv[jt][r], 1);
                if ((lane & 1) == 0) {
                    ushort2v u2;
                    u2.x = f2bf(pv[jt][r]);
                    u2.y = f2bf(other);
                    int frag = (w*2 + (jt >> 1))*64
                             + ((2*jt + (m >> 3)) & 3)*16 + 4*g + r;
                    *(ushort2v*)&PA[buf][frag*8 + (m & 7)] = u2;
                }
            }

        __syncthreads();

#pragma unroll
        for (int rt = 0; rt < 4; ++rt) {
            floatx4 a4 = *(const floatx4*)&AL[buf][16*rt + 4*g];
#pragma unroll
            for (int ct = 0; ct < 4; ++ct)
                accO[rt][ct] *= a4;
        }
#pragma unroll
        for (int ks = 0; ks < 2; ++ks) {
            bf16x8 pf[4];
#pragma unroll
            for (int rt = 0; rt < 4; ++rt)
                pf[rt] = *(const bf16x8*)&PA[buf][((rt*2 + ks)*64 + lane)*8];
#pragma unroll
            for (int ct = 0; ct < 4; ++ct)
#pragma unroll
                for (int rt = 0; rt < 4; ++rt)
                    accO[rt][ct] = __builtin_amdgcn_mfma_f32_16x16x32_bf16(
                                       pf[rt], vf[ks][ct], accO[rt][ct], 0, 0, 0);
        }
    }

    // ---- store unnormalized partial O (bf16) and per-row m,l ----
    const size_t tbase = ((size_t)(half*B_ + b)*64 + tile);
    unsigned short* Ob = Opart + tbase * (C_ * 64);
    float* ml = ML + tbase * 128;

    if (m == 0) {
        floatx4 m4 = {mrow[0], mrow[1], mrow[2], mrow[3]};
        floatx4 l4 = {lrow[0], lrow[1], lrow[2], lrow[3]};
        *(floatx4*)&ml[16*w + 4*g]      = m4;
        *(floatx4*)&ml[64 + 16*w + 4*g] = l4;
    }

#pragma unroll
    for (int rt = 0; rt < 4; ++rt)
#pragma unroll
        for (int ct = 0; ct < 4; ++ct) {
            int c = 64*w + 16*ct + m;
            ushort4v u4;
#pragma unroll
            for (int r = 0; r < 4; ++r) u4[r] = f2bf(accO[rt][ct][r]);
            *(ushort4v*)(Ob + (size_t)c*64 + 16*rt + 4*g) = u4;
        }
}

// ---------------------------------------------------------------------------
// Combine: out[b][c][n0+j] = gamma*(f0[j]*O0[c][j] + f1[j]*O1[c][j]) + x,
// f_h = e^{m_h - M} / L, L = e^{m0-M} l0 + e^{m1-M} l1.
// ---------------------------------------------------------------------------
__global__ __launch_bounds__(256) void combine_kernel(
    const unsigned short* __restrict__ Opart, const float* __restrict__ ML,
    const float* __restrict__ x, const float* __restrict__ gamma,
    float* __restrict__ out)
{
    __shared__ float sc[2][64];
    const int tile = blockIdx.x;
    const int b    = blockIdx.y;
    const int n0   = tile * 64;
    const int t    = threadIdx.x;

    if (t < 64) {
        const float* ml0 = ML + ((size_t)(0*B_ + b)*64 + tile)*128;
        const float* ml1 = ML + ((size_t)(1*B_ + b)*64 + tile)*128;
        float m0 = ml0[t], l0 = ml0[64 + t];
        float m1 = ml1[t], l1 = ml1[64 + t];
        float M  = fmaxf(m0, m1);
        float f0 = __expf(m0 - M), f1 = __expf(m1 - M);
        float L  = f0*l0 + f1*l1;
        float gm = gamma[0];
        sc[0][t] = gm * f0 / L;
        sc[1][t] = gm * f1 / L;
    }
    __syncthreads();

    const int nq = t & 15;        // n-quad: n = 4*nq..4*nq+3
    const int c0 = t >> 4;        // c = 16*i + c0
    const unsigned short* O0 = Opart + ((size_t)(0*B_ + b)*64 + tile)*(C_*64);
    const unsigned short* O1 = Opart + ((size_t)(1*B_ + b)*64 + tile)*(C_*64);
    const float* xb = x   + (size_t)b*C_*N_;
    float*       ob = out + (size_t)b*C_*N_;

    float s0[4], s1[4];
#pragma unroll
    for (int k = 0; k < 4; ++k) { s0[k] = sc[0][4*nq + k]; s1[k] = sc[1][4*nq + k]; }

#pragma unroll 4
    for (int i = 0; i < 16; ++i) {
        int c = 16*i + c0;
        ushort4v a4 = *(const ushort4v*)(O0 + (size_t)c*64 + 4*nq);
        ushort4v b4 = *(const ushort4v*)(O1 + (size_t)c*64 + 4*nq);
        float4 x4 = *(const float4*)(xb + (size_t)c*N_ + n0 + 4*nq);
        float4 y;
        y.x = s0[0]*bf2f(a4[0]) + s1[0]*bf2f(b4[0]) + x4.x;
        y.y = s0[1]*bf2f(a4[1]) + s1[1]*bf2f(b4[1]) + x4.y;
        y.z = s0[2]*bf2f(a4[2]) + s1[2]*bf2f(b4[2]) + x4.z;
        y.w = s0[3]*bf2f(a4[3]) + s1[3]*bf2f(b4[3]) + x4.w;
        *(float4*)(ob + (size_t)c*N_ + n0 + 4*nq) = y;
    }
}

// ---------------------------------------------------------------------------
extern "C" void kernel_launch(void* const* d_in, const int* in_sizes, int n_in,
                              void* d_out, int out_size, void* d_ws, size_t ws_size,
                              hipStream_t stream) {
    const float* x     = (const float*)d_in[0];
    const float* Wq    = (const float*)d_in[1];
    const float* bq    = (const float*)d_in[2];
    const float* Wk    = (const float*)d_in[3];
    const float* bk    = (const float*)d_in[4];
    const float* Wv    = (const float*)d_in[5];
    const float* bv    = (const float*)d_in[6];
    const float* gamma = (const float*)d_in[7];
    float* out = (float*)d_out;

    unsigned short* Qg = (unsigned short*)d_ws;          // [B][N][64]   2 MB
    unsigned short* Kg = Qg + (size_t)B_*N_*D_;          // [B][N][64]   2 MB
    unsigned short* Vg = Kg + (size_t)B_*N_*D_;          // [B][C][N]    8 MB
    unsigned short* Op = Vg + (size_t)B_*C_*N_;          // partials    16 MB
    float*          ML = (float*)(Op + (size_t)2*B_*64*C_*64); // m,l   256 KB

    proj_kernel<<<dim3(3, 32, 4), 256, 0, stream>>>(x, Wq, bq, Wk, bk, Wv, bv,
                                                    Qg, Kg, Vg);
    flash_kernel<<<dim3(64, 2, 4), 256, 0, stream>>>(Qg, Kg, Vg, Op, ML);
    combine_kernel<<<dim3(64, 4), 256, 0, stream>>>(Op, ML, x, gamma, out);
}